// Round 11
// baseline (93.638 us; speedup 1.0000x reference)
//
#include <hip/hip_runtime.h>
#include <hip/hip_bf16.h>

#define NSTATES 8
#define HD      1024
#define NBATCH  16384
#define NT      16      // K-tiles of 64

// output layout (flat fp32, return order)
#define OUT_MEAS 0
#define OUT_CP   16777216
#define OUT_ENT  16777224
#define OUT_COH  16777225
#define OUT_AD   16777226
#define OUT_PH   16785418

typedef __attribute__((ext_vector_type(8))) short short8;
typedef __attribute__((ext_vector_type(4))) float f32x4;

__device__ __forceinline__ short f2bf(float f) {
    union { float f; unsigned u; } x; x.f = f;
    unsigned r = x.u + 0x7fffu + ((x.u >> 16) & 1u);  // RNE
    return (short)(r >> 16);
}

__device__ __forceinline__ unsigned cvtpk(float lo, float hi) {
    unsigned r;
    asm("v_cvt_pk_bf16_f32 %0, %1, %2" : "=v"(r) : "v"(lo), "v"(hi));
    return r;
}

__device__ __forceinline__ short8 pack8pk(float4 a, float4 b) {
    union { unsigned u[4]; short8 s; } r;
    r.u[0] = cvtpk(a.x, a.y);
    r.u[1] = cvtpk(a.z, a.w);
    r.u[2] = cvtpk(b.x, b.y);
    r.u[3] = cvtpk(b.z, b.w);
    return r.s;
}

// ---------------- K1: amplitude pipeline (1 block, 1024 threads) ----------------
__global__ __launch_bounds__(1024) void k_amps(const float* __restrict__ AR,
                                               const float* __restrict__ AI,
                                               const float* __restrict__ H,
                                               float* __restrict__ out,
                                               float* __restrict__ w) {
    __shared__ float redA[16 * NSTATES];
    __shared__ float redB[16 * 10];
    __shared__ float norms[NSTATES];
    __shared__ float sA[8][8], sA2[8][8], sA3[8][8];
    __shared__ float Ur[8][8], Ui[8][8];
    __shared__ float lamsa[2];

    const int tid = threadIdx.x;
    const int lane = tid & 63, wid = tid >> 6;
    const int d = tid;

    float arv[NSTATES], aiv[NSTATES];
    #pragma unroll
    for (int s = 0; s < NSTATES; s++) {
        arv[s] = AR[s * HD + d];
        aiv[s] = AI[s * HD + d];
    }
    float p[NSTATES];
    #pragma unroll
    for (int s = 0; s < NSTATES; s++) p[s] = arv[s] * arv[s] + aiv[s] * aiv[s];
    #pragma unroll
    for (int s = 0; s < NSTATES; s++)
        #pragma unroll
        for (int o = 32; o > 0; o >>= 1) p[s] += __shfl_down(p[s], o, 64);
    if (lane == 0)
        #pragma unroll
        for (int s = 0; s < NSTATES; s++) redA[wid * NSTATES + s] = p[s];
    if (tid < 64) {
        int i = tid >> 3, j = tid & 7;
        sA[i][j] = 0.5f * (H[i * 8 + j] + H[j * 8 + i]) * 0.01f;  // DT/PLANCK
    }
    __syncthreads();
    if (tid < 8) {
        float acc = 0.f;
        #pragma unroll
        for (int v = 0; v < 16; v++) acc += redA[v * NSTATES + tid];
        norms[tid] = acc;
    }
    if (tid < 64) {
        int i = tid >> 3, j = tid & 7;
        float acc = 0.f;
        #pragma unroll
        for (int k = 0; k < 8; k++) acc += sA[i][k] * sA[k][j];
        sA2[i][j] = acc;
    }
    __syncthreads();
    if (tid < 64) {
        int i = tid >> 3, j = tid & 7;
        float acc = 0.f;
        #pragma unroll
        for (int k = 0; k < 8; k++) acc += sA2[i][k] * sA[k][j];
        sA3[i][j] = acc;
        Ur[i][j] = ((i == j) ? 1.f : 0.f) - 0.5f * sA2[i][j];   // cos(A)
        Ui[i][j] = -(sA[i][j] - sA3[i][j] * (1.f / 6.f));       // -sin(A)
    }
    __syncthreads();

    #pragma unroll
    for (int s = 0; s < NSTATES; s++) {
        float inv = 1.0f / sqrtf(norms[s] + 1e-8f);
        arv[s] *= inv;
        aiv[s] *= inv;
    }
    float nr[NSTATES], ni[NSTATES];
    #pragma unroll
    for (int s = 0; s < NSTATES; s++) {
        float xr = 0.f, xi = 0.f;
        #pragma unroll
        for (int t = 0; t < NSTATES; t++) {
            float ur = Ur[s][t], ui = Ui[s][t];
            xr += ur * arv[t] - ui * aiv[t];
            xi += ur * aiv[t] + ui * arv[t];
        }
        nr[s] = xr; ni[s] = xi;
    }
    float dist[NSTATES], csum = 0.f, sabs = 0.f;
    #pragma unroll
    for (int s = 0; s < NSTATES; s++) {
        dist[s] = nr[s] * nr[s] + ni[s] * ni[s];
        csum += dist[s];
        sabs += sqrtf(dist[s]);
    }
    #pragma unroll
    for (int s = 0; s < NSTATES; s++) {
        out[OUT_AD + s * HD + d] = dist[s];
        out[OUT_PH + s * HD + d] = atan2f(ni[s], nr[s]);
        w[s * HD + d] = nr[s];
    }
    float cinv = 1.0f / (csum + 1e-8f);
    float q[10];
    #pragma unroll
    for (int s = 0; s < NSTATES; s++) q[s] = dist[s] * cinv;
    q[8] = csum; q[9] = sabs;
    #pragma unroll
    for (int v = 0; v < 10; v++)
        #pragma unroll
        for (int o = 32; o > 0; o >>= 1) q[v] += __shfl_down(q[v], o, 64);
    if (lane == 0)
        #pragma unroll
        for (int v = 0; v < 10; v++) redB[wid * 10 + v] = q[v];
    __syncthreads();
    if (tid < 10) {
        float acc = 0.f;
        #pragma unroll
        for (int v = 0; v < 16; v++) acc += redB[v * 10 + tid];
        if (tid < 8)       out[OUT_CP + tid] = acc * (1.0f / HD);
        else               lamsa[tid - 8] = acc;
    }
    __syncthreads();
    if (tid == 0) {
        float lam = lamsa[0], sa = lamsa[1];
        out[OUT_ENT] = -(lam * logf(lam + 1e-12f));
        out[OUT_COH] = sa * sa - lam;
    }
}

// ------- K3: fused project + transpose: Mt[e,d] = bf16( sum_s w[s,e]*P[s,d,e] ) -
__global__ __launch_bounds__(256) void k_project_t(const float* __restrict__ P,
                                                   const float* __restrict__ w,
                                                   short* __restrict__ Mt) {
    __shared__ float tile[64][65];
    int d0 = (blockIdx.x >> 4) * 64;
    int e0 = (blockIdx.x & 15) * 64;
    int tx = threadIdx.x & 63, ty = threadIdx.x >> 6;
    float wv[NSTATES];
    #pragma unroll
    for (int s = 0; s < NSTATES; s++) wv[s] = w[s * HD + e0 + tx];
    #pragma unroll
    for (int j = 0; j < 16; j++) {
        int r = ty + 4 * j;
        float acc = 0.f;
        #pragma unroll
        for (int s = 0; s < NSTATES; s++)
            acc += wv[s] * P[(size_t)s * HD * HD + (size_t)(d0 + r) * HD + e0 + tx];
        tile[r][tx] = acc;
    }
    __syncthreads();
    #pragma unroll
    for (int j = 0; j < 16; j++) {
        int er = ty + 4 * j;
        Mt[(size_t)(e0 + er) * HD + d0 + tx] = f2bf(tile[tx][er]);
    }
}

// -------- K4: out = bf16(X) @ Mt^T -- 256^2 JIT-A with 4-phase X lookahead -----
// 512 threads = 8 waves (2M x 4N per 128x128 quadrant). A is JIT-cast from fp32
// X: TWO register windows; issue X(t+2) in ph1/ph2 of tile t, ds_write X(t+1)
// in ph3/ph4 (4-phase issue->consume distance covers HBM latency). B staged by
// global_load_lds; B-lo moved to ph1 so the tile-end counted vmcnt(10) never
// forces the young X loads. One MID barrier per phase; B-lo frags persist
// ph1->ph4; A,B double-buffered (128 KiB LDS); both-sides XOR swizzle.

__device__ __forceinline__ void stage_half_B(const short* __restrict__ srcBase,
                                             int rowbase, int h, int t2,
                                             short* dst, const int* goff,
                                             const int* ldsoff) {
    #pragma unroll
    for (int i = 0; i < 2; i++) {
        const short* g = srcBase + (size_t)(rowbase + h * 128) * HD + t2 * 64 + goff[i];
        __builtin_amdgcn_global_load_lds(
            (const __attribute__((address_space(1))) void*)g,
            (__attribute__((address_space(3))) void*)(dst + h * 8192 + ldsoff[i]),
            16, 0, 0);
    }
}

#define XLOAD(dst, h, t2)                                                      \
    {                                                                          \
        const float* b_ = X + (size_t)(brow + (h) * 128) * HD + (t2) * 64;     \
        dst[0] = *reinterpret_cast<const float4*>(b_ + goff[0]);               \
        dst[1] = *reinterpret_cast<const float4*>(b_ + goff[0] + 4);           \
        dst[2] = *reinterpret_cast<const float4*>(b_ + goff[1]);               \
        dst[3] = *reinterpret_cast<const float4*>(b_ + goff[1] + 4);           \
    }

#define XWRITE(dstlds, src)                                                    \
    {                                                                          \
        *reinterpret_cast<short8*>((dstlds) + ldsoff[0]) = pack8pk(src[0], src[1]); \
        *reinterpret_cast<short8*>((dstlds) + ldsoff[1]) = pack8pk(src[2], src[3]); \
    }

#define LOAD_A(qa)                                                             \
    _Pragma("unroll") for (int mf = 0; mf < 4; mf++)                           \
    _Pragma("unroll") for (int kk = 0; kk < 2; kk++)                           \
        af[mf][kk] = *reinterpret_cast<const short8*>(                         \
            &Acur[((qa) * 128 + wr64 + mf * 16 + ln15) * 64 + kx[kk]]);

#define LOAD_B_TO(dst, qb)                                                     \
    _Pragma("unroll") for (int nf = 0; nf < 2; nf++)                           \
    _Pragma("unroll") for (int kk = 0; kk < 2; kk++)                           \
        dst[nf][kk] = *reinterpret_cast<const short8*>(                        \
            &Bcur[((qb) * 128 + wn32 + nf * 16 + ln15) * 64 + kx[kk]]);

#define MFMA_P(qa, qb, breg)                                                   \
    _Pragma("unroll") for (int mf = 0; mf < 4; mf++)                           \
    _Pragma("unroll") for (int nf = 0; nf < 2; nf++)                           \
    _Pragma("unroll") for (int kk = 0; kk < 2; kk++)                           \
        acc[(qa) * 4 + mf][(qb) * 2 + nf] =                                    \
            __builtin_amdgcn_mfma_f32_16x16x32_bf16(                           \
                af[mf][kk], breg[nf][kk], acc[(qa) * 4 + mf][(qb) * 2 + nf], 0, 0, 0);

// One K-tile, 4 phases. WIL/WIH: window receiving X(t+2) issues.
// WWL/WWH: window holding X(t+1), ds_written to Anext in ph3/ph4.
#define TILE_BODY(t, WIL, WIH, WWL, WWH)                                       \
    {                                                                          \
        const int cur = (t) & 1;                                               \
        short* Acur  = cur ? A1b : A0;                                         \
        short* Bcur  = cur ? B1b : B0;                                         \
        short* Anext = cur ? A0 : A1b;                                         \
        short* Bnext = cur ? B0 : B1b;                                         \
        /* ph1: (A0,B-lo); DMA B-lo(t+1); issue X-lo(t+2) */                   \
        LOAD_A(0); LOAD_B_TO(bfL, 0);                                          \
        if ((t) + 1 < NT) stage_half_B(Mt, bcol, 0, (t) + 1, Bnext, goff, ldsoff); \
        if ((t) + 2 < NT) XLOAD(WIL, 0, (t) + 2);                              \
        __builtin_amdgcn_s_barrier();                                          \
        __builtin_amdgcn_s_setprio(1);                                         \
        MFMA_P(0, 0, bfL);                                                     \
        __builtin_amdgcn_s_setprio(0);                                         \
        /* ph2: (A0,B-hi); issue X-hi(t+2) */                                  \
        LOAD_B_TO(bfH, 1);                                                     \
        if ((t) + 2 < NT) XLOAD(WIH, 1, (t) + 2);                              \
        __builtin_amdgcn_s_barrier();                                          \
        __builtin_amdgcn_s_setprio(1);                                         \
        MFMA_P(0, 1, bfH);                                                     \
        __builtin_amdgcn_s_setprio(0);                                         \
        /* ph3: (A1,B-hi); write A-lo(t+1) from WWL (loaded 4 phases ago) */   \
        LOAD_A(1);                                                             \
        if ((t) + 1 < NT) XWRITE(Anext, WWL);                                  \
        __builtin_amdgcn_s_barrier();                                          \
        __builtin_amdgcn_s_setprio(1);                                         \
        MFMA_P(1, 1, bfH);                                                     \
        __builtin_amdgcn_s_setprio(0);                                         \
        /* ph4: (A1,B-lo) [bfL persists]; write A-hi(t+1); DMA B-hi(t+2) */    \
        if ((t) + 1 < NT) XWRITE(Anext + 8192, WWH);                           \
        if ((t) + 2 < NT) stage_half_B(Mt, bcol, 1, (t) + 2, Bcur, goff, ldsoff); \
        /* outstanding 14 = {Bhi(t+1):2, Blo(t+1):2, X(t+2):8, Bhi(t+2):2}; */ \
        /* oldest 4 done => all of B(t+1) resident. lgkm publishes A writes. */\
        if ((t) + 2 < NT)      asm volatile("s_waitcnt vmcnt(10) lgkmcnt(0)" ::: "memory"); \
        else if ((t) + 1 < NT) asm volatile("s_waitcnt vmcnt(0) lgkmcnt(0)" ::: "memory");  \
        __builtin_amdgcn_s_barrier();                                          \
        __builtin_amdgcn_s_setprio(1);                                         \
        MFMA_P(1, 0, bfL);                                                     \
        __builtin_amdgcn_s_setprio(0);                                         \
    }

__global__ __launch_bounds__(512, 1) void k_gemm_jit2(const float* __restrict__ X,
                                                      const short* __restrict__ Mt,
                                                      float* __restrict__ out) {
    __shared__ short As[2][256 * 64];   // 64 KiB: [buf][half*128+row][kchunk]
    __shared__ short Bs[2][256 * 64];   // 64 KiB

    const int bid = blockIdx.x;                       // 256 blocks (64 bm x 4 bn)
    const int swz = (bid & 7) * 32 + (bid >> 3);      // XCD-contiguous, bijective
    const int brow = (swz >> 2) * 256;
    const int bcol = (swz & 3) * 256;

    const int tid  = threadIdx.x;
    const int lane = tid & 63, wid = tid >> 6;
    const int wr = wid >> 2, wn = wid & 3;
    const int ln15 = lane & 15, l16 = lane >> 4;
    const int wr64 = wr * 64;
    const int wn32 = wn * 32;

    // ds_read swizzled k-chunk offsets (shorts): chunk = kg ^ (row&7); row&7==ln15&7
    int kx[2];
    kx[0] = ((l16 + 0) ^ (ln15 & 7)) * 8;
    kx[1] = ((l16 + 4) ^ (ln15 & 7)) * 8;

    // staging offsets (elements): LDS linear dest, inverse-swizzled global source
    int goff[2], ldsoff[2];
    #pragma unroll
    for (int i = 0; i < 2; i++) {
        int c = tid + 512 * i;
        int row = c >> 3, kc = c & 7;
        goff[i]   = row * HD + ((kc ^ (row & 7)) * 8);
        ldsoff[i] = c * 8;
    }

    short* A0 = &As[0][0]; short* A1b = &As[1][0];
    short* B0 = &Bs[0][0]; short* B1b = &Bs[1][0];

    f32x4 acc[8][4];
    #pragma unroll
    for (int m = 0; m < 8; m++)
        #pragma unroll
        for (int n = 0; n < 4; n++) acc[m][n] = (f32x4){0.f, 0.f, 0.f, 0.f};

    float4 W0L[4], W0H[4], W1L[4], W1H[4];   // two X staging windows

    // ---- prologue ----
    XLOAD(W0L, 0, 0);                        // X(0)
    XLOAD(W0H, 1, 0);
    stage_half_B(Mt, bcol, 0, 0, B0, goff, ldsoff);   // B(0)
    stage_half_B(Mt, bcol, 1, 0, B0, goff, ldsoff);
    stage_half_B(Mt, bcol, 1, 1, B1b, goff, ldsoff);  // B-hi(1)
    XWRITE(A0, W0L);                         // implicit vmcnt drains X(0)
    XWRITE(A0 + 8192, W0H);
    XLOAD(W1L, 0, 1);                        // X(1) -> written during tile 0
    XLOAD(W1H, 1, 1);
    // outstanding: [B(0):4, B-hi(1):2, X(1):8] = 14; need B(0) -> vmcnt(10);
    // lgkmcnt(0) publishes A0 writes.
    asm volatile("s_waitcnt vmcnt(10) lgkmcnt(0)" ::: "memory");
    __builtin_amdgcn_s_barrier();

    short8 af[4][2], bfL[2][2], bfH[2][2];

    #pragma unroll 1
    for (int tt = 0; tt < NT; tt += 2) {
        TILE_BODY(tt,     W0L, W0H, W1L, W1H);   // even: issue into W0, write W1
        TILE_BODY(tt + 1, W1L, W1H, W0L, W0H);   // odd:  issue into W1, write W0
    }

    // epilogue: C/D layout col=lane&15, row=(lane>>4)*4+j  [m89-verified]
    #pragma unroll
    for (int qa = 0; qa < 2; qa++)
        #pragma unroll
        for (int mf = 0; mf < 4; mf++)
            #pragma unroll
            for (int qb = 0; qb < 2; qb++)
                #pragma unroll
                for (int nf = 0; nf < 2; nf++)
                    #pragma unroll
                    for (int j = 0; j < 4; j++) {
                        int r = brow + qa * 128 + wr64 + mf * 16 + l16 * 4 + j;
                        int c = bcol + qb * 128 + wn32 + nf * 16 + ln15;
                        out[(size_t)r * HD + c] = acc[qa * 4 + mf][qb * 2 + nf][j];
                    }
}

extern "C" void kernel_launch(void* const* d_in, const int* in_sizes, int n_in,
                              void* d_out, int out_size, void* d_ws, size_t ws_size,
                              hipStream_t stream) {
    const float* X  = (const float*)d_in[0];  // [16384,1024]
    const float* AR = (const float*)d_in[1];
    const float* AI = (const float*)d_in[2];
    const float* H  = (const float*)d_in[3];
    const float* P  = (const float*)d_in[4];  // [8,1024,1024]
    float* out = (float*)d_out;

    char* ws = (char*)d_ws;
    float* w  = (float*)ws;                       // 32 KB
    short* Mt = (short*)(ws + 32768);             // 2 MB  (bf16 M^T)

    k_amps<<<1, 1024, 0, stream>>>(AR, AI, H, out, w);
    k_project_t<<<256, 256, 0, stream>>>(P, w, Mt);
    k_gemm_jit2<<<(NBATCH / 256) * (HD / 256), 512, 0, stream>>>(X, Mt, out);
}

// Round 12
// 83.169 us; speedup vs baseline: 1.1259x; 1.1259x over previous
//
#include <hip/hip_runtime.h>
#include <hip/hip_bf16.h>

#define NSTATES 8
#define HD      1024
#define NBATCH  16384
#define NT      16      // K-tiles of 64

// output layout (flat fp32, return order)
#define OUT_MEAS 0
#define OUT_CP   16777216
#define OUT_ENT  16777224
#define OUT_COH  16777225
#define OUT_AD   16777226
#define OUT_PH   16785418

typedef __attribute__((ext_vector_type(8))) short short8;
typedef __attribute__((ext_vector_type(4))) float f32x4;

__device__ __forceinline__ short f2bf(float f) {
    union { float f; unsigned u; } x; x.f = f;
    unsigned r = x.u + 0x7fffu + ((x.u >> 16) & 1u);  // RNE
    return (short)(r >> 16);
}

__device__ __forceinline__ short8 pack8(float4 a, float4 b) {
    short8 v;
    v[0] = f2bf(a.x); v[1] = f2bf(a.y); v[2] = f2bf(a.z); v[3] = f2bf(a.w);
    v[4] = f2bf(b.x); v[5] = f2bf(b.y); v[6] = f2bf(b.z); v[7] = f2bf(b.w);
    return v;
}

// ---- K_PRE2: one launch, three block roles (all independent):
//   [0,256)        : project+transpose -> Mt, with norms+U recomputed locally
//   [256,8448)     : Xb = bf16(X) cast
//   8448           : amplitude-metrics outputs (AD/PH/CP/ENT/COH)
__global__ __launch_bounds__(256) void k_pre2(const float* __restrict__ X,
                                              short* __restrict__ Xb,
                                              const float* __restrict__ P,
                                              const float* __restrict__ AR,
                                              const float* __restrict__ AI,
                                              const float* __restrict__ H,
                                              short* __restrict__ Mt,
                                              float* __restrict__ out) {
    const int bid = blockIdx.x;
    const int tid = threadIdx.x;

    // ---------------- cast role (majority of blocks) ----------------
    if (bid >= 256 && bid < 256 + 8192) {
        int idx = (bid - 256) * 256 + tid;            // chunk of 8 elems
        const float* src = X + (size_t)idx * 8;
        float4 f0 = *reinterpret_cast<const float4*>(src);
        float4 f1 = *reinterpret_cast<const float4*>(src + 4);
        *reinterpret_cast<short8*>(Xb + (size_t)idx * 8) = pack8(f0, f1);
        return;
    }

    // ---------------- shared state for norms + U (project & amps roles) ----
    __shared__ float redN[4][NSTATES];
    __shared__ float norms[NSTATES];
    __shared__ float sA[8][8], sA2[8][8];
    __shared__ float Ur[8][8], Ui[8][8];
    __shared__ float tile[64][65];        // project staging (also pads LDS)
    __shared__ float redC[4][10];
    __shared__ float lamsa[2];

    const int lane = tid & 63, wid = tid >> 6;

    // norms: each thread covers d = tid + c*256
    float p[NSTATES];
    #pragma unroll
    for (int s = 0; s < NSTATES; s++) p[s] = 0.f;
    #pragma unroll
    for (int c = 0; c < 4; c++) {
        int d = tid + c * 256;
        #pragma unroll
        for (int s = 0; s < NSTATES; s++) {
            float a = AR[s * HD + d], b = AI[s * HD + d];
            p[s] += a * a + b * b;
        }
    }
    #pragma unroll
    for (int s = 0; s < NSTATES; s++)
        #pragma unroll
        for (int o = 32; o > 0; o >>= 1) p[s] += __shfl_down(p[s], o, 64);
    if (lane == 0)
        #pragma unroll
        for (int s = 0; s < NSTATES; s++) redN[wid][s] = p[s];
    if (tid < 64) {
        int i = tid >> 3, j = tid & 7;
        sA[i][j] = 0.5f * (H[i * 8 + j] + H[j * 8 + i]) * 0.01f;  // DT/PLANCK
    }
    __syncthreads();
    if (tid < 8)
        norms[tid] = redN[0][tid] + redN[1][tid] + redN[2][tid] + redN[3][tid];
    if (tid < 64) {
        int i = tid >> 3, j = tid & 7;
        float acc = 0.f;
        #pragma unroll
        for (int k = 0; k < 8; k++) acc += sA[i][k] * sA[k][j];
        sA2[i][j] = acc;
    }
    __syncthreads();
    if (tid < 64) {
        int i = tid >> 3, j = tid & 7;
        float a3 = 0.f;
        #pragma unroll
        for (int k = 0; k < 8; k++) a3 += sA2[i][k] * sA[k][j];
        Ur[i][j] = ((i == j) ? 1.f : 0.f) - 0.5f * sA2[i][j];   // cos(A)
        Ui[i][j] = -(sA[i][j] - a3 * (1.f / 6.f));              // -sin(A)
    }
    __syncthreads();

    if (bid < 256) {
        // ---------------- project role ----------------
        int d0 = (bid >> 4) * 64;
        int e0 = (bid & 15) * 64;
        int tx = tid & 63, ty = tid >> 6;
        // local w[s, e0+tx]
        float inv[NSTATES], arv[NSTATES], aiv[NSTATES], wv[NSTATES];
        #pragma unroll
        for (int s = 0; s < NSTATES; s++) inv[s] = 1.0f / sqrtf(norms[s] + 1e-8f);
        #pragma unroll
        for (int s = 0; s < NSTATES; s++) {
            arv[s] = AR[s * HD + e0 + tx] * inv[s];
            aiv[s] = AI[s * HD + e0 + tx] * inv[s];
        }
        #pragma unroll
        for (int s = 0; s < NSTATES; s++) {
            float xr = 0.f;
            #pragma unroll
            for (int t = 0; t < NSTATES; t++)
                xr += Ur[s][t] * arv[t] - Ui[s][t] * aiv[t];
            wv[s] = xr;
        }
        #pragma unroll
        for (int j = 0; j < 16; j++) {
            int r = ty + 4 * j;
            float acc = 0.f;
            #pragma unroll
            for (int s = 0; s < NSTATES; s++)
                acc += wv[s] * P[(size_t)s * HD * HD + (size_t)(d0 + r) * HD + e0 + tx];
            tile[r][tx] = acc;
        }
        __syncthreads();
        #pragma unroll
        for (int j = 0; j < 16; j++) {
            int er = ty + 4 * j;
            Mt[(size_t)(e0 + er) * HD + d0 + tx] = f2bf(tile[tx][er]);
        }
        return;
    }

    // ---------------- amps role (bid == 8448) ----------------
    float inv[NSTATES];
    #pragma unroll
    for (int s = 0; s < NSTATES; s++) inv[s] = 1.0f / sqrtf(norms[s] + 1e-8f);
    float q[10];
    #pragma unroll
    for (int v = 0; v < 10; v++) q[v] = 0.f;
    #pragma unroll
    for (int c = 0; c < 4; c++) {
        int d = tid + c * 256;
        float arv[NSTATES], aiv[NSTATES], nr[NSTATES], ni[NSTATES];
        #pragma unroll
        for (int s = 0; s < NSTATES; s++) {
            arv[s] = AR[s * HD + d] * inv[s];
            aiv[s] = AI[s * HD + d] * inv[s];
        }
        #pragma unroll
        for (int s = 0; s < NSTATES; s++) {
            float xr = 0.f, xi = 0.f;
            #pragma unroll
            for (int t = 0; t < NSTATES; t++) {
                float ur = Ur[s][t], ui = Ui[s][t];
                xr += ur * arv[t] - ui * aiv[t];
                xi += ur * aiv[t] + ui * arv[t];
            }
            nr[s] = xr; ni[s] = xi;
        }
        float dist[NSTATES], csum = 0.f, sabs = 0.f;
        #pragma unroll
        for (int s = 0; s < NSTATES; s++) {
            dist[s] = nr[s] * nr[s] + ni[s] * ni[s];
            csum += dist[s];
            sabs += sqrtf(dist[s]);
        }
        #pragma unroll
        for (int s = 0; s < NSTATES; s++) {
            out[OUT_AD + s * HD + d] = dist[s];
            out[OUT_PH + s * HD + d] = atan2f(ni[s], nr[s]);
        }
        float cinv = 1.0f / (csum + 1e-8f);
        #pragma unroll
        for (int s = 0; s < NSTATES; s++) q[s] += dist[s] * cinv;
        q[8] += csum; q[9] += sabs;
    }
    #pragma unroll
    for (int v = 0; v < 10; v++)
        #pragma unroll
        for (int o = 32; o > 0; o >>= 1) q[v] += __shfl_down(q[v], o, 64);
    if (lane == 0)
        #pragma unroll
        for (int v = 0; v < 10; v++) redC[wid][v] = q[v];
    __syncthreads();
    if (tid < 10) {
        float acc = redC[0][tid] + redC[1][tid] + redC[2][tid] + redC[3][tid];
        if (tid < 8)       out[OUT_CP + tid] = acc * (1.0f / HD);
        else               lamsa[tid - 8] = acc;
    }
    __syncthreads();
    if (tid == 0) {
        float lam = lamsa[0], sa = lamsa[1];
        out[OUT_ENT] = -(lam * logf(lam + 1e-12f));
        out[OUT_COH] = sa * sa - lam;
    }
}

// ---------------- K4: out = Xb @ Mt^T -- R7-proven dephased quadrant-phase -----
// 512 threads = 8 waves (2M x 4N per 128x128 quadrant). All-DMA staging.
// ONE MID barrier per phase + tile-end vmcnt barrier; B-lo frags persist
// ph1->ph4 (24 ds_read_b128/tile); both-sides XOR swizzle; XCD swizzle.

__device__ __forceinline__ void stage_half(const short* __restrict__ srcBase,
                                           int rowbase, int h, int t2,
                                           short* dst, const int* goff,
                                           const int* ldsoff) {
    #pragma unroll
    for (int i = 0; i < 2; i++) {
        const short* g = srcBase + (size_t)(rowbase + h * 128) * HD + t2 * 64 + goff[i];
        __builtin_amdgcn_global_load_lds(
            (const __attribute__((address_space(1))) void*)g,
            (__attribute__((address_space(3))) void*)(dst + h * 8192 + ldsoff[i]),
            16, 0, 0);
    }
}

#define LOAD_A(qa)                                                             \
    _Pragma("unroll") for (int mf = 0; mf < 4; mf++)                           \
    _Pragma("unroll") for (int kk = 0; kk < 2; kk++)                           \
        af[mf][kk] = *reinterpret_cast<const short8*>(                         \
            &Acur[((qa) * 128 + wr64 + mf * 16 + ln15) * 64 + kx[kk]]);

#define LOAD_B_TO(dst, qb)                                                     \
    _Pragma("unroll") for (int nf = 0; nf < 2; nf++)                           \
    _Pragma("unroll") for (int kk = 0; kk < 2; kk++)                           \
        dst[nf][kk] = *reinterpret_cast<const short8*>(                        \
            &Bcur[((qb) * 128 + wn32 + nf * 16 + ln15) * 64 + kx[kk]]);

#define MFMA_P(qa, qb, breg)                                                   \
    _Pragma("unroll") for (int mf = 0; mf < 4; mf++)                           \
    _Pragma("unroll") for (int nf = 0; nf < 2; nf++)                           \
    _Pragma("unroll") for (int kk = 0; kk < 2; kk++)                           \
        acc[(qa) * 4 + mf][(qb) * 2 + nf] =                                    \
            __builtin_amdgcn_mfma_f32_16x16x32_bf16(                           \
                af[mf][kk], breg[nf][kk], acc[(qa) * 4 + mf][(qb) * 2 + nf], 0, 0, 0);

__global__ __launch_bounds__(512, 1) void k_gemm_8p(const short* __restrict__ Xb,
                                                    const short* __restrict__ Mt,
                                                    float* __restrict__ out) {
    __shared__ short As[2][256 * 64];   // 64 KiB: [buf][half*128+row][kchunk]
    __shared__ short Bs[2][256 * 64];   // 64 KiB

    const int bid = blockIdx.x;                       // 256 blocks (64 bm x 4 bn)
    const int swz = (bid & 7) * 32 + (bid >> 3);      // XCD-contiguous, bijective
    const int brow = (swz >> 2) * 256;
    const int bcol = (swz & 3) * 256;

    const int tid  = threadIdx.x;
    const int lane = tid & 63, wid = tid >> 6;
    const int wr = wid >> 2, wn = wid & 3;
    const int ln15 = lane & 15, l16 = lane >> 4;
    const int wr64 = wr * 64;
    const int wn32 = wn * 32;

    // ds_read swizzled k-chunk offsets (shorts): chunk = kg ^ (row&7); row&7==ln15&7
    int kx[2];
    kx[0] = ((l16 + 0) ^ (ln15 & 7)) * 8;
    kx[1] = ((l16 + 4) ^ (ln15 & 7)) * 8;

    // staging offsets (elements): LDS linear dest, inverse-swizzled global source
    int goff[2], ldsoff[2];
    #pragma unroll
    for (int i = 0; i < 2; i++) {
        int c = tid + 512 * i;
        int row = c >> 3, kc = c & 7;
        goff[i]   = row * HD + ((kc ^ (row & 7)) * 8);
        ldsoff[i] = c * 8;
    }

    short* A0 = &As[0][0]; short* A1b = &As[1][0];
    short* B0 = &Bs[0][0]; short* B1b = &Bs[1][0];

    f32x4 acc[8][4];
    #pragma unroll
    for (int m = 0; m < 8; m++)
        #pragma unroll
        for (int n = 0; n < 4; n++) acc[m][n] = (f32x4){0.f, 0.f, 0.f, 0.f};

    // prologue: tile0 (4 halves) + A-lo(1) + B-hi(1)  [12 loads]
    stage_half(Xb, brow, 0, 0, A0, goff, ldsoff);
    stage_half(Xb, brow, 1, 0, A0, goff, ldsoff);
    stage_half(Mt, bcol, 0, 0, B0, goff, ldsoff);
    stage_half(Mt, bcol, 1, 0, B0, goff, ldsoff);
    stage_half(Xb, brow, 0, 1, A1b, goff, ldsoff);
    stage_half(Mt, bcol, 1, 1, B1b, goff, ldsoff);
    asm volatile("s_waitcnt vmcnt(4)" ::: "memory");  // tile0's 8 loads landed
    __builtin_amdgcn_s_barrier();

    short8 af[4][2], bfL[2][2], bfH[2][2];

    #pragma unroll 1
    for (int t = 0; t < NT; t++) {
        const int cur = t & 1;
        short* Acur  = cur ? A1b : A0;
        short* Bcur  = cur ? B1b : B0;
        short* Anext = cur ? A0 : A1b;   // buf of t+1
        short* Bnext = cur ? B0 : B1b;

        // ---- ph1: quadrant (0,0); stage A-hi(t+1)
        LOAD_A(0); LOAD_B_TO(bfL, 0);
        if (t + 1 < NT) stage_half(Xb, brow, 1, t + 1, Anext, goff, ldsoff);
        __builtin_amdgcn_s_barrier();
        __builtin_amdgcn_s_setprio(1);
        MFMA_P(0, 0, bfL);
        __builtin_amdgcn_s_setprio(0);

        // ---- ph2: quadrant (0,1); stage B-lo(t+1)
        LOAD_B_TO(bfH, 1);
        if (t + 1 < NT) stage_half(Mt, bcol, 0, t + 1, Bnext, goff, ldsoff);
        __builtin_amdgcn_s_barrier();
        __builtin_amdgcn_s_setprio(1);
        MFMA_P(0, 1, bfH);
        __builtin_amdgcn_s_setprio(0);

        // ---- ph3: quadrant (1,1); stage A-lo(t+2) into cur freed slot
        LOAD_A(1);
        if (t + 2 < NT) stage_half(Xb, brow, 0, t + 2, Acur, goff, ldsoff);
        __builtin_amdgcn_s_barrier();
        __builtin_amdgcn_s_setprio(1);
        MFMA_P(1, 1, bfH);
        __builtin_amdgcn_s_setprio(0);

        // ---- ph4: quadrant (1,0) [read-free: bfL persists]; stage B-hi(t+2)
        if (t + 2 < NT) stage_half(Mt, bcol, 1, t + 2, Bcur, goff, ldsoff);
        // outstanding 8 = {A-hi(t+1):2, B-lo(t+1):2, A-lo(t+2):2, B-hi(t+2):2};
        // oldest 4 done => tile t+1 fully resident.
        if (t + 2 < NT)      asm volatile("s_waitcnt vmcnt(4)" ::: "memory");
        else if (t + 1 < NT) asm volatile("s_waitcnt vmcnt(0)" ::: "memory");
        __builtin_amdgcn_s_barrier();
        __builtin_amdgcn_s_setprio(1);
        MFMA_P(1, 0, bfL);
        __builtin_amdgcn_s_setprio(0);
    }

    // epilogue: C/D layout col=lane&15, row=(lane>>4)*4+j  [m89-verified]
    #pragma unroll
    for (int qa = 0; qa < 2; qa++)
        #pragma unroll
        for (int mf = 0; mf < 4; mf++)
            #pragma unroll
            for (int qb = 0; qb < 2; qb++)
                #pragma unroll
                for (int nf = 0; nf < 2; nf++)
                    #pragma unroll
                    for (int j = 0; j < 4; j++) {
                        int r = brow + qa * 128 + wr64 + mf * 16 + l16 * 4 + j;
                        int c = bcol + qb * 128 + wn32 + nf * 16 + ln15;
                        out[(size_t)r * HD + c] = acc[qa * 4 + mf][qb * 2 + nf][j];
                    }
}

extern "C" void kernel_launch(void* const* d_in, const int* in_sizes, int n_in,
                              void* d_out, int out_size, void* d_ws, size_t ws_size,
                              hipStream_t stream) {
    const float* X  = (const float*)d_in[0];  // [16384,1024]
    const float* AR = (const float*)d_in[1];
    const float* AI = (const float*)d_in[2];
    const float* H  = (const float*)d_in[3];
    const float* P  = (const float*)d_in[4];  // [8,1024,1024]
    float* out = (float*)d_out;

    char* ws = (char*)d_ws;
    short* Mt = (short*)ws;                       // 2 MB  (bf16 M^T)
    short* Xb = (short*)(ws + 2097152);           // 32 MB (bf16 X)

    k_pre2<<<256 + 8192 + 1, 256, 0, stream>>>(X, Xb, P, AR, AI, H, Mt, out);
    k_gemm_8p<<<(NBATCH / 256) * (HD / 256), 512, 0, stream>>>(Xb, Mt, out);
}

// Round 13
// 71.760 us; speedup vs baseline: 1.3049x; 1.1590x over previous
//
#include <hip/hip_runtime.h>
#include <hip/hip_bf16.h>

#define NSTATES 8
#define HD      1024
#define NBATCH  16384
#define NT      16      // K-tiles of 64

// output layout (flat fp32, return order)
#define OUT_MEAS 0
#define OUT_CP   16777216
#define OUT_ENT  16777224
#define OUT_COH  16777225
#define OUT_AD   16777226
#define OUT_PH   16785418

typedef __attribute__((ext_vector_type(8))) short short8;
typedef __attribute__((ext_vector_type(4))) float f32x4;

__device__ __forceinline__ short f2bf(float f) {
    union { float f; unsigned u; } x; x.f = f;
    unsigned r = x.u + 0x7fffu + ((x.u >> 16) & 1u);  // RNE
    return (short)(r >> 16);
}

__device__ __forceinline__ unsigned cvtpk(float lo, float hi) {
    unsigned r;
    asm("v_cvt_pk_bf16_f32 %0, %1, %2" : "=v"(r) : "v"(lo), "v"(hi));
    return r;
}

__device__ __forceinline__ short8 pack8pk(float4 a, float4 b) {
    union { unsigned u[4]; short8 s; } r;
    r.u[0] = cvtpk(a.x, a.y);
    r.u[1] = cvtpk(a.z, a.w);
    r.u[2] = cvtpk(b.x, b.y);
    r.u[3] = cvtpk(b.z, b.w);
    return r.s;
}

// ---------------- K1: amplitude pipeline (1 block, 1024 threads) ----------------
__global__ __launch_bounds__(1024) void k_amps(const float* __restrict__ AR,
                                               const float* __restrict__ AI,
                                               const float* __restrict__ H,
                                               float* __restrict__ out,
                                               float* __restrict__ w) {
    __shared__ float redA[16 * NSTATES];
    __shared__ float redB[16 * 10];
    __shared__ float norms[NSTATES];
    __shared__ float sA[8][8], sA2[8][8], sA3[8][8];
    __shared__ float Ur[8][8], Ui[8][8];
    __shared__ float lamsa[2];

    const int tid = threadIdx.x;
    const int lane = tid & 63, wid = tid >> 6;
    const int d = tid;

    float arv[NSTATES], aiv[NSTATES];
    #pragma unroll
    for (int s = 0; s < NSTATES; s++) {
        arv[s] = AR[s * HD + d];
        aiv[s] = AI[s * HD + d];
    }
    float p[NSTATES];
    #pragma unroll
    for (int s = 0; s < NSTATES; s++) p[s] = arv[s] * arv[s] + aiv[s] * aiv[s];
    #pragma unroll
    for (int s = 0; s < NSTATES; s++)
        #pragma unroll
        for (int o = 32; o > 0; o >>= 1) p[s] += __shfl_down(p[s], o, 64);
    if (lane == 0)
        #pragma unroll
        for (int s = 0; s < NSTATES; s++) redA[wid * NSTATES + s] = p[s];
    if (tid < 64) {
        int i = tid >> 3, j = tid & 7;
        sA[i][j] = 0.5f * (H[i * 8 + j] + H[j * 8 + i]) * 0.01f;  // DT/PLANCK
    }
    __syncthreads();
    if (tid < 8) {
        float acc = 0.f;
        #pragma unroll
        for (int v = 0; v < 16; v++) acc += redA[v * NSTATES + tid];
        norms[tid] = acc;
    }
    if (tid < 64) {
        int i = tid >> 3, j = tid & 7;
        float acc = 0.f;
        #pragma unroll
        for (int k = 0; k < 8; k++) acc += sA[i][k] * sA[k][j];
        sA2[i][j] = acc;
    }
    __syncthreads();
    if (tid < 64) {
        int i = tid >> 3, j = tid & 7;
        float acc = 0.f;
        #pragma unroll
        for (int k = 0; k < 8; k++) acc += sA2[i][k] * sA[k][j];
        sA3[i][j] = acc;
        Ur[i][j] = ((i == j) ? 1.f : 0.f) - 0.5f * sA2[i][j];   // cos(A)
        Ui[i][j] = -(sA[i][j] - sA3[i][j] * (1.f / 6.f));       // -sin(A)
    }
    __syncthreads();

    #pragma unroll
    for (int s = 0; s < NSTATES; s++) {
        float inv = 1.0f / sqrtf(norms[s] + 1e-8f);
        arv[s] *= inv;
        aiv[s] *= inv;
    }
    float nr[NSTATES], ni[NSTATES];
    #pragma unroll
    for (int s = 0; s < NSTATES; s++) {
        float xr = 0.f, xi = 0.f;
        #pragma unroll
        for (int t = 0; t < NSTATES; t++) {
            float ur = Ur[s][t], ui = Ui[s][t];
            xr += ur * arv[t] - ui * aiv[t];
            xi += ur * aiv[t] + ui * arv[t];
        }
        nr[s] = xr; ni[s] = xi;
    }
    float dist[NSTATES], csum = 0.f, sabs = 0.f;
    #pragma unroll
    for (int s = 0; s < NSTATES; s++) {
        dist[s] = nr[s] * nr[s] + ni[s] * ni[s];
        csum += dist[s];
        sabs += sqrtf(dist[s]);
    }
    #pragma unroll
    for (int s = 0; s < NSTATES; s++) {
        out[OUT_AD + s * HD + d] = dist[s];
        out[OUT_PH + s * HD + d] = atan2f(ni[s], nr[s]);
        w[s * HD + d] = nr[s];
    }
    float cinv = 1.0f / (csum + 1e-8f);
    float q[10];
    #pragma unroll
    for (int s = 0; s < NSTATES; s++) q[s] = dist[s] * cinv;
    q[8] = csum; q[9] = sabs;
    #pragma unroll
    for (int v = 0; v < 10; v++)
        #pragma unroll
        for (int o = 32; o > 0; o >>= 1) q[v] += __shfl_down(q[v], o, 64);
    if (lane == 0)
        #pragma unroll
        for (int v = 0; v < 10; v++) redB[wid * 10 + v] = q[v];
    __syncthreads();
    if (tid < 10) {
        float acc = 0.f;
        #pragma unroll
        for (int v = 0; v < 16; v++) acc += redB[v * 10 + tid];
        if (tid < 8)       out[OUT_CP + tid] = acc * (1.0f / HD);
        else               lamsa[tid - 8] = acc;
    }
    __syncthreads();
    if (tid == 0) {
        float lam = lamsa[0], sa = lamsa[1];
        out[OUT_ENT] = -(lam * logf(lam + 1e-12f));
        out[OUT_COH] = sa * sa - lam;
    }
}

// ------- K3: fused project + transpose: Mt[e,d] = bf16( sum_s w[s,e]*P[s,d,e] ) -
__global__ __launch_bounds__(256) void k_project_t(const float* __restrict__ P,
                                                   const float* __restrict__ w,
                                                   short* __restrict__ Mt) {
    __shared__ float tile[64][65];
    int d0 = (blockIdx.x >> 4) * 64;
    int e0 = (blockIdx.x & 15) * 64;
    int tx = threadIdx.x & 63, ty = threadIdx.x >> 6;
    float wv[NSTATES];
    #pragma unroll
    for (int s = 0; s < NSTATES; s++) wv[s] = w[s * HD + e0 + tx];
    #pragma unroll
    for (int j = 0; j < 16; j++) {
        int r = ty + 4 * j;
        float acc = 0.f;
        #pragma unroll
        for (int s = 0; s < NSTATES; s++)
            acc += wv[s] * P[(size_t)s * HD * HD + (size_t)(d0 + r) * HD + e0 + tx];
        tile[r][tx] = acc;
    }
    __syncthreads();
    #pragma unroll
    for (int j = 0; j < 16; j++) {
        int er = ty + 4 * j;
        Mt[(size_t)(e0 + er) * HD + d0 + tx] = f2bf(tile[tx][er]);
    }
}

// -------- K4: out = bf16(X) @ Mt^T -- 256^2 JIT-A with 3-PHASE X lookahead -----
// 512 threads = 8 waves (2M x 4N per 128x128 quadrant). Same as R9's schedule
// but X issue points moved one phase earlier (pure reorder, window stays 32
// VGPR): xrH(t+1) issued ph1(t), written ph4(t); xrL(t+2) issued ph4(t),
// written ph3(t+1) -- both 3-phase issue->consume. B staged by global_load_lds
// (B-lo(t+1) @ph2, B-hi(t+2) @ph4). One MID barrier/phase; bfL persists
// ph1->ph4; A,B double-buffered (128 KiB); both-sides XOR swizzle; XCD swizzle.
// FIFO waits: ph3 XWRITE implicit vmcnt(2) [drains xrL, leaves B-lo(t+1)];
// ph4 XWRITE implicit vmcnt(2) [drains xrH]; explicit vmcnt(6)+lgkm(0) at ph4
// [drains B-lo(t+1), leaves xrL(t+2):4 + B-hi(t+2):2, publishes A writes].

__device__ __forceinline__ void stage_half_B(const short* __restrict__ srcBase,
                                             int rowbase, int h, int t2,
                                             short* dst, const int* goff,
                                             const int* ldsoff) {
    #pragma unroll
    for (int i = 0; i < 2; i++) {
        const short* g = srcBase + (size_t)(rowbase + h * 128) * HD + t2 * 64 + goff[i];
        __builtin_amdgcn_global_load_lds(
            (const __attribute__((address_space(1))) void*)g,
            (__attribute__((address_space(3))) void*)(dst + h * 8192 + ldsoff[i]),
            16, 0, 0);
    }
}

#define XLOAD(dst, h, t2)                                                      \
    {                                                                          \
        const float* b_ = X + (size_t)(brow + (h) * 128) * HD + (t2) * 64;     \
        dst[0] = *reinterpret_cast<const float4*>(b_ + goff[0]);               \
        dst[1] = *reinterpret_cast<const float4*>(b_ + goff[0] + 4);           \
        dst[2] = *reinterpret_cast<const float4*>(b_ + goff[1]);               \
        dst[3] = *reinterpret_cast<const float4*>(b_ + goff[1] + 4);           \
    }

#define XWRITE(dstlds, src)                                                    \
    {                                                                          \
        *reinterpret_cast<short8*>((dstlds) + ldsoff[0]) = pack8pk(src[0], src[1]); \
        *reinterpret_cast<short8*>((dstlds) + ldsoff[1]) = pack8pk(src[2], src[3]); \
    }

#define LOAD_A(qa)                                                             \
    _Pragma("unroll") for (int mf = 0; mf < 4; mf++)                           \
    _Pragma("unroll") for (int kk = 0; kk < 2; kk++)                           \
        af[mf][kk] = *reinterpret_cast<const short8*>(                         \
            &Acur[((qa) * 128 + wr64 + mf * 16 + ln15) * 64 + kx[kk]]);

#define LOAD_B_TO(dst, qb)                                                     \
    _Pragma("unroll") for (int nf = 0; nf < 2; nf++)                           \
    _Pragma("unroll") for (int kk = 0; kk < 2; kk++)                           \
        dst[nf][kk] = *reinterpret_cast<const short8*>(                        \
            &Bcur[((qb) * 128 + wn32 + nf * 16 + ln15) * 64 + kx[kk]]);

#define MFMA_P(qa, qb, breg)                                                   \
    _Pragma("unroll") for (int mf = 0; mf < 4; mf++)                           \
    _Pragma("unroll") for (int nf = 0; nf < 2; nf++)                           \
    _Pragma("unroll") for (int kk = 0; kk < 2; kk++)                           \
        acc[(qa) * 4 + mf][(qb) * 2 + nf] =                                    \
            __builtin_amdgcn_mfma_f32_16x16x32_bf16(                           \
                af[mf][kk], breg[nf][kk], acc[(qa) * 4 + mf][(qb) * 2 + nf], 0, 0, 0);

__global__ __launch_bounds__(512, 1) void k_gemm_jit3(const float* __restrict__ X,
                                                      const short* __restrict__ Mt,
                                                      float* __restrict__ out) {
    __shared__ short As[2][256 * 64];   // 64 KiB: [buf][half*128+row][kchunk]
    __shared__ short Bs[2][256 * 64];   // 64 KiB

    const int bid = blockIdx.x;                       // 256 blocks (64 bm x 4 bn)
    const int swz = (bid & 7) * 32 + (bid >> 3);      // XCD-contiguous, bijective
    const int brow = (swz >> 2) * 256;
    const int bcol = (swz & 3) * 256;

    const int tid  = threadIdx.x;
    const int lane = tid & 63, wid = tid >> 6;
    const int wr = wid >> 2, wn = wid & 3;
    const int ln15 = lane & 15, l16 = lane >> 4;
    const int wr64 = wr * 64;
    const int wn32 = wn * 32;

    // ds_read swizzled k-chunk offsets (shorts): chunk = kg ^ (row&7); row&7==ln15&7
    int kx[2];
    kx[0] = ((l16 + 0) ^ (ln15 & 7)) * 8;
    kx[1] = ((l16 + 4) ^ (ln15 & 7)) * 8;

    // staging offsets (elements): LDS linear dest, inverse-swizzled global source
    int goff[2], ldsoff[2];
    #pragma unroll
    for (int i = 0; i < 2; i++) {
        int c = tid + 512 * i;
        int row = c >> 3, kc = c & 7;
        goff[i]   = row * HD + ((kc ^ (row & 7)) * 8);
        ldsoff[i] = c * 8;
    }

    short* A0 = &As[0][0]; short* A1b = &As[1][0];
    short* B0 = &Bs[0][0]; short* B1b = &Bs[1][0];

    f32x4 acc[8][4];
    #pragma unroll
    for (int m = 0; m < 8; m++)
        #pragma unroll
        for (int n = 0; n < 4; n++) acc[m][n] = (f32x4){0.f, 0.f, 0.f, 0.f};

    float4 xrL[4], xrH[4];   // X windows: xrL = lo-half, xrH = hi-half

    // ---- prologue: A(0) via reg+write; B(0); B-hi(1); xrL <- lo(1) ----
    XLOAD(xrL, 0, 0);
    XLOAD(xrH, 1, 0);
    stage_half_B(Mt, bcol, 0, 0, B0, goff, ldsoff);
    stage_half_B(Mt, bcol, 1, 0, B0, goff, ldsoff);
    stage_half_B(Mt, bcol, 1, 1, B1b, goff, ldsoff);
    XWRITE(A0, xrL);            // implicit vmcnt drains X(0) loads
    XWRITE(A0 + 8192, xrH);
    XLOAD(xrL, 0, 1);           // lo(1), written at ph3(0)
    // outstanding: [B(0):4, B-hi(1):2, xrL:4]; need B(0) -> vmcnt(6);
    // lgkmcnt(0) publishes A0 writes.
    asm volatile("s_waitcnt vmcnt(6) lgkmcnt(0)" ::: "memory");
    __builtin_amdgcn_s_barrier();

    short8 af[4][2], bfL[2][2], bfH[2][2];

    #pragma unroll 1
    for (int t = 0; t < NT; t++) {
        const int cur = t & 1;
        short* Acur  = cur ? A1b : A0;
        short* Bcur  = cur ? B1b : B0;
        short* Anext = cur ? A0 : A1b;   // buf of t+1
        short* Bnext = cur ? B0 : B1b;

        // ---- ph1: quadrant (0,0); issue X-hi(t+1) (3-phase lead to ph4)
        LOAD_A(0); LOAD_B_TO(bfL, 0);
        if (t + 1 < NT) XLOAD(xrH, 1, (t + 1));
        __builtin_amdgcn_s_barrier();
        __builtin_amdgcn_s_setprio(1);
        MFMA_P(0, 0, bfL);
        __builtin_amdgcn_s_setprio(0);

        // ---- ph2: quadrant (0,1); DMA B-lo(t+1)
        LOAD_B_TO(bfH, 1);
        if (t + 1 < NT) stage_half_B(Mt, bcol, 0, t + 1, Bnext, goff, ldsoff);
        __builtin_amdgcn_s_barrier();
        __builtin_amdgcn_s_setprio(1);
        MFMA_P(0, 1, bfH);
        __builtin_amdgcn_s_setprio(0);

        // ---- ph3: quadrant (1,1); write A-lo(t+1) from xrL (issued ph4(t-1))
        LOAD_A(1);
        if (t + 1 < NT) XWRITE(Anext, xrL);   // implicit vmcnt(2): leaves B-lo
        __builtin_amdgcn_s_barrier();
        __builtin_amdgcn_s_setprio(1);
        MFMA_P(1, 1, bfH);
        __builtin_amdgcn_s_setprio(0);

        // ---- ph4: quadrant (1,0) [read-free: bfL persists];
        //      write A-hi(t+1) from xrH (issued ph1(t)); issue X-lo(t+2);
        //      DMA B-hi(t+2) into cur freed slot
        if (t + 1 < NT) XWRITE(Anext + 8192, xrH);  // implicit vmcnt(2): drains xrH
        if (t + 2 < NT) {
            XLOAD(xrL, 0, (t + 2));                 // 3-phase lead to ph3(t+1)
            stage_half_B(Mt, bcol, 1, t + 2, Bcur, goff, ldsoff);
        }
        // outstanding: [B-lo(t+1):2, xrL(t+2):4, B-hi(t+2):2] = 8;
        // vmcnt(6) drains B-lo(t+1); lgkmcnt(0) publishes both A-half writes.
        if (t + 2 < NT)      asm volatile("s_waitcnt vmcnt(6) lgkmcnt(0)" ::: "memory");
        else if (t + 1 < NT) asm volatile("s_waitcnt vmcnt(0) lgkmcnt(0)" ::: "memory");
        __builtin_amdgcn_s_barrier();
        __builtin_amdgcn_s_setprio(1);
        MFMA_P(1, 0, bfL);
        __builtin_amdgcn_s_setprio(0);
    }

    // epilogue: C/D layout col=lane&15, row=(lane>>4)*4+j  [m89-verified]
    #pragma unroll
    for (int qa = 0; qa < 2; qa++)
        #pragma unroll
        for (int mf = 0; mf < 4; mf++)
            #pragma unroll
            for (int qb = 0; qb < 2; qb++)
                #pragma unroll
                for (int nf = 0; nf < 2; nf++)
                    #pragma unroll
                    for (int j = 0; j < 4; j++) {
                        int r = brow + qa * 128 + wr64 + mf * 16 + l16 * 4 + j;
                        int c = bcol + qb * 128 + wn32 + nf * 16 + ln15;
                        out[(size_t)r * HD + c] = acc[qa * 4 + mf][qb * 2 + nf][j];
                    }
}

extern "C" void kernel_launch(void* const* d_in, const int* in_sizes, int n_in,
                              void* d_out, int out_size, void* d_ws, size_t ws_size,
                              hipStream_t stream) {
    const float* X  = (const float*)d_in[0];  // [16384,1024]
    const float* AR = (const float*)d_in[1];
    const float* AI = (const float*)d_in[2];
    const float* H  = (const float*)d_in[3];
    const float* P  = (const float*)d_in[4];  // [8,1024,1024]
    float* out = (float*)d_out;

    char* ws = (char*)d_ws;
    float* w  = (float*)ws;                       // 32 KB
    short* Mt = (short*)(ws + 32768);             // 2 MB  (bf16 M^T)

    k_amps<<<1, 1024, 0, stream>>>(AR, AI, H, out, w);
    k_project_t<<<256, 256, 0, stream>>>(P, w, Mt);
    k_gemm_jit3<<<(NBATCH / 256) * (HD / 256), 512, 0, stream>>>(X, Mt, out);
}